// Round 1
// 204.367 us; speedup vs baseline: 1.1913x; 1.1913x over previous
//
#include <hip/hip_runtime.h>
#include <hip/hip_bf16.h>

// Shapes (hard-coded per setup_inputs): b=8, c=128, p=2048, h=4, c*h=512
#define NB 8
#define NC 128
#define NP 2048
#define NH 4
#define NCH 512

typedef __attribute__((ext_vector_type(8))) short bf16x8;   // MFMA A/B frag (4 VGPR)
typedef __attribute__((ext_vector_type(16))) float f32x16;  // MFMA C/D (16 VGPR)

__device__ __forceinline__ float bf2f(unsigned short u) {
  return __uint_as_float(((unsigned)u) << 16);
}
__device__ __forceinline__ unsigned short f2bf(float f) {
  __hip_bfloat16 h = __float2bfloat16(f);   // RNE
  return *reinterpret_cast<unsigned short*>(&h);
}
__device__ __forceinline__ unsigned pk2(float lo, float hi) {
  return (unsigned)f2bf(lo) | ((unsigned)f2bf(hi) << 16);
}
// async 16B global->LDS (HW writes lane i at wave-uniform base + i*16)
__device__ __forceinline__ void gload_lds16(const void* g, void* l) {
  __builtin_amdgcn_global_load_lds(
      (const __attribute__((address_space(1))) void*)g,
      (__attribute__((address_space(3))) void*)l, 16, 0, 0);
}
// v_permlane32_swap: a' = [a.lo32, b.lo32], b' = [a.hi32, b.hi32]
__device__ __forceinline__ void plswap(unsigned& a, unsigned& b) {
  asm volatile("v_permlane32_swap_b32 %0, %1" : "+v"(a), "+v"(b));
}

// --------------------------------------------------------------- bn partial --
__global__ __launch_bounds__(256) void bn_partial(
    const float* __restrict__ in, float* __restrict__ psum,
    float* __restrict__ psum2) {
  int c = blockIdx.x >> 2, qtr = blockIdx.x & 3;
  int t = threadIdx.x;
  float s = 0.f, s2 = 0.f;
  for (int b = 0; b < NB; ++b) {
    const float* ptr = in + ((size_t)b * NC + c) * NP + qtr * 512;
    #pragma unroll
    for (int p = 0; p < 2; ++p) {
      float v = ptr[p * 256 + t];
      s += v; s2 += v * v;
    }
  }
  for (int off = 32; off; off >>= 1) {
    s += __shfl_down(s, off, 64);
    s2 += __shfl_down(s2, off, 64);
  }
  __shared__ float red[8];
  int lane = t & 63, wid = t >> 6;
  if (!lane) { red[wid] = s; red[wid + 4] = s2; }
  __syncthreads();
  if (!t) {
    psum[blockIdx.x] = red[0] + red[1] + red[2] + red[3];
    psum2[blockIdx.x] = red[4] + red[5] + red[6] + red[7];
  }
}

// ---------------------------------------------------------------- qkv proj --
// MFMA GEMM: [1536 o x 64 p] per block, K=128. X^T staged once (bf16).
// V written [b][o][p] (natural for PV A-operand).
// Q/K written TRANSPOSED [b][h][p][c] via MFMA operand swap (A/B 32x32 frags
// have identical lane->element maps, so the same regs serve either role):
// acc = mfma(Xfrag, Wfrag) -> D[m=p][n=o]. attn then stages K linearly.
// q pre-scaled by 128^-0.5 * log2(e).
__global__ __launch_bounds__(512, 2) void qkv_proj(
    const float* __restrict__ in, const float* __restrict__ gamma,
    const float* __restrict__ beta, const float* __restrict__ psum,
    const float* __restrict__ psum2, const float* __restrict__ Wq,
    const float* __restrict__ bq, const float* __restrict__ Wk,
    const float* __restrict__ bk, const float* __restrict__ Wv,
    const float* __restrict__ bv, unsigned short* __restrict__ qws,
    unsigned short* __restrict__ kws, unsigned short* __restrict__ vws) {
  __shared__ float sc[128], sh[128], bias[1536];
  __shared__ __align__(16) unsigned short Xt[64][136];  // [p][c], 272B pitch
  int t = threadIdx.x;
  int pt = blockIdx.x & 31, b = blockIdx.x >> 5;
  int p0 = pt * 64;
  if (t < 128) {  // bn finalize
    float s = psum[t * 4] + psum[t * 4 + 1] + psum[t * 4 + 2] + psum[t * 4 + 3];
    float s2 = psum2[t * 4] + psum2[t * 4 + 1] + psum2[t * 4 + 2] + psum2[t * 4 + 3];
    const float invn = 1.f / (NB * NP);
    float mean = s * invn, var = s2 * invn - mean * mean;
    float scl = gamma[t] * rsqrtf(var + 1e-5f);
    sc[t] = scl; sh[t] = beta[t] - mean * scl;
  }
  bias[t] = bq[t]; bias[512 + t] = bk[t]; bias[1024 + t] = bv[t];
  __syncthreads();
  {  // stage X^T (read input once, coalesced), normalize, bf16
    int p = t & 63, c0 = (t >> 6) * 16;
    const float* src = in + ((size_t)b * NC + c0) * NP + p0 + p;
    #pragma unroll
    for (int cc = 0; cc < 16; ++cc) {
      float v = src[(size_t)cc * NP];
      Xt[p][c0 + cc] = f2bf(v * sc[c0 + cc] + sh[c0 + cc]);
    }
  }
  __syncthreads();
  int w = t >> 6, lane = t & 63, l31 = lane & 31, h5 = lane >> 5;
  #pragma unroll 1
  for (int s = 0; s < 3; ++s) {
    int strip = s * 8 + w;                 // 24 strips of 64 o; proj uniform per s
    int proj = strip >> 3, within = (strip & 7) * 64;
    const float* W = proj == 0 ? Wq : (proj == 1 ? Wk : Wv);
    f32x16 acc[2][2] = {};
    #pragma unroll
    for (int ks = 0; ks < 8; ++ks) {
      bf16x8 af[2], bf[2];
      #pragma unroll
      for (int mt = 0; mt < 2; ++mt) {
        const float* wr = W + (size_t)(within + mt * 32 + l31) * NC + ks * 16 + h5 * 8;
        float4 a = *(const float4*)wr, b4 = *(const float4*)(wr + 4);
        union { bf16x8 v; unsigned u[4]; } uu;
        uu.u[0] = pk2(a.x, a.y); uu.u[1] = pk2(a.z, a.w);
        uu.u[2] = pk2(b4.x, b4.y); uu.u[3] = pk2(b4.z, b4.w);
        af[mt] = uu.v;
      }
      #pragma unroll
      for (int nt = 0; nt < 2; ++nt)
        bf[nt] = *(const bf16x8*)&Xt[nt * 32 + l31][ks * 16 + h5 * 8];
      if (proj < 2) {      // transposed: D[m=p][n=o]
        #pragma unroll
        for (int mt = 0; mt < 2; ++mt)
          #pragma unroll
          for (int nt = 0; nt < 2; ++nt)
            acc[mt][nt] = __builtin_amdgcn_mfma_f32_32x32x16_bf16(bf[nt], af[mt], acc[mt][nt], 0, 0, 0);
      } else {             // original: D[m=o][n=p]
        #pragma unroll
        for (int mt = 0; mt < 2; ++mt)
          #pragma unroll
          for (int nt = 0; nt < 2; ++nt)
            acc[mt][nt] = __builtin_amdgcn_mfma_f32_32x32x16_bf16(af[mt], bf[nt], acc[mt][nt], 0, 0, 0);
      }
    }
    if (proj < 2) {
      // write [b][h][p][c]; o = c*4 + h. Lanes cover 32 consecutive o =
      // 4 heads x 8-c 16B chunks; L2 merges into full lines (same CU/XCD).
      unsigned short* dst = proj == 0 ? qws : kws;
      float qs = proj == 0 ? 0.12751743762765621f : 1.0f;
      #pragma unroll
      for (int mt = 0; mt < 2; ++mt) {
        int o = within + mt * 32 + l31;
        float bs = bias[proj * 512 + o];
        unsigned short* drow = dst + ((size_t)(b * 4 + (o & 3)) * NP) * NC + (o >> 2);
        #pragma unroll
        for (int nt = 0; nt < 2; ++nt)
          #pragma unroll
          for (int r = 0; r < 16; ++r) {
            int p = p0 + nt * 32 + (r & 3) + 8 * (r >> 2) + 4 * h5;
            drow[(size_t)p * NC] = f2bf((acc[mt][nt][r] + bs) * qs);
          }
      }
    } else {
      #pragma unroll
      for (int mt = 0; mt < 2; ++mt)
        #pragma unroll
        for (int nt = 0; nt < 2; ++nt)
          #pragma unroll
          for (int r = 0; r < 16; ++r) {
            int oo = within + mt * 32 + (r & 3) + 8 * (r >> 2) + 4 * h5;
            float val = acc[mt][nt][r] + bias[1024 + oo];
            vws[((size_t)(b * NCH + oo)) * NP + p0 + nt * 32 + l31] = f2bf(val);
          }
    }
  }
}

// --------------------------------------------------------------- attention --
// 256 thr = 4 waves, each owning 32 i-rows (block i-tile 128); j-tile 64.
// Q^T/K^T arrive in [b][h][p][c] -> staging is LINEAR (no in-kernel transpose).
// Double-buffered async staging via global_load_lds (LDS dest linear,
// inverse-swizzled global source, chunk^row XOR swizzle on read) -> Kt/Vs
// b128 reads ~conflict-free, ONE barrier per j-tile.
// P-pack cross-half exchange via v_permlane32_swap (VALU) instead of
// ds_bpermute shuffles (LDS pipe).
// C/D 32x32: col=lane&31, row=(reg&3)+8*(reg>>2)+4*(lane>>5)  [m74/m101]
__global__ __launch_bounds__(256, 2) void attn(
    const unsigned short* __restrict__ qT, const unsigned short* __restrict__ kT,
    const unsigned short* __restrict__ vws, unsigned short* __restrict__ attws) {
  // K tile: [64 j][16 chunks of 8c], slot = j*16 + (chunk ^ (j&15))
  // V tile: [64 rowpairs r=c>>1][16 chunks], chunk = (c&1)*8 + j>>3,
  //         slot = r*16 + (chunk ^ (r&15))
  __shared__ uint4 Kbuf[2][1024];   // 2 x 16KB
  __shared__ uint4 Vbuf[2][1024];   // 2 x 16KB  (total 64KB)
  int tid = threadIdx.x;
  int wl = tid >> 6, lane = tid & 63, l31 = lane & 31, h5 = lane >> 5;
  int bid = blockIdx.x;
  int head = bid & 31, it = bid >> 5;      // same head -> same XCD (bid%8 const)
  int b = head >> 2, hh = head & 3;
  int i0 = it * 128;
  const unsigned short* krow = kT + (size_t)(b * 4 + hh) * NP * NC;
  const unsigned short* vb = vws + (size_t)b * NCH * NP;

  // DMA decode: per call k, linear LDS slot s = k*256 + tid.
  // K: row j = k*16 + t4 (+j0), holds chunk ch = (tid&15)^(t4&15).
  // V: rowpair r = k*16 + t4 -> c = r*2 + (ch>>3), j-chunk = (ch&7)*8.
  int t4 = tid >> 4;
  int ch = (tid & 15) ^ (t4 & 15);
  size_t vO = ((size_t)((t4 * 2 + (ch >> 3)) * 4 + hh)) * NP + (ch & 7) * 8;

  auto stage = [&](int bi, int j0v) {
    #pragma unroll
    for (int k = 0; k < 4; ++k) {
      gload_lds16(krow + (size_t)(j0v + k * 16 + t4) * NC + (ch << 3),
                  &Kbuf[bi][k * 256 + tid]);
      gload_lds16(vb + vO + (size_t)k * 128 * NP + j0v,
                  &Vbuf[bi][k * 256 + tid]);
    }
  };

  // Q fragments: B-operand (lane col = i), vector loads from Q^T rows
  bf16x8 qf[8];
  {
    const unsigned short* qp =
        qT + ((size_t)(b * 4 + hh) * NP + (i0 + wl * 32 + l31)) * NC + h5 * 8;
    #pragma unroll
    for (int ks = 0; ks < 8; ++ks) qf[ks] = *(const bf16x8*)(qp + ks * 16);
  }

  f32x16 oacc[4] = {};
  float lsum = 0.f;

  stage(0, 0);
  __syncthreads();                 // drains DMA (vmcnt) + barrier

  int kbase = l31 * 16, ksw = l31 & 15;
  #pragma unroll 1
  for (int tI = 0; tI < 32; ++tI) {
    int cur = tI & 1;
    if (tI < 31) stage(cur ^ 1, (tI + 1) * 64);

    // ---- S^T tiles [32 j][32 i], both ntj interleaved (2 MFMA chains) ----
    f32x16 sacT0 = {}, sacT1 = {};
    #pragma unroll
    for (int ks = 0; ks < 8; ++ks) {
      int cidx = (ks * 2 + h5) ^ ksw;
      bf16x8 kf0 = *(const bf16x8*)&Kbuf[cur][kbase + cidx];
      bf16x8 kf1 = *(const bf16x8*)&Kbuf[cur][512 + kbase + cidx];
      sacT0 = __builtin_amdgcn_mfma_f32_32x32x16_bf16(kf0, qf[ks], sacT0, 0, 0, 0);
      sacT1 = __builtin_amdgcn_mfma_f32_32x32x16_bf16(kf1, qf[ks], sacT1, 0, 0, 0);
    }
    // ---- exp2, l partial, pack P^T B-frags via permlane32_swap ----
    bf16x8 pfrag[4];
    #pragma unroll
    for (int ntj = 0; ntj < 2; ++ntj) {
      f32x16& sacT = ntj ? sacT1 : sacT0;
      #pragma unroll
      for (int r = 0; r < 16; ++r) {
        sacT[r] = __builtin_amdgcn_exp2f(sacT[r]);
        lsum += sacT[r];
      }
      unsigned wv[8];
      #pragma unroll
      for (int q = 0; q < 8; ++q) wv[q] = pk2(sacT[q * 2], sacT[q * 2 + 1]);
      // after swap(a,b): a=[a.lo,b.lo], b=[a.hi,b.hi] -> exactly the
      // {own, partner} words each half needs, no selects required.
      plswap(wv[0], wv[2]); plswap(wv[1], wv[3]);
      plswap(wv[4], wv[6]); plswap(wv[5], wv[7]);
      union { bf16x8 v; unsigned u[4]; } f0, f1;
      f0.u[0] = wv[0]; f0.u[1] = wv[1]; f0.u[2] = wv[2]; f0.u[3] = wv[3];
      f1.u[0] = wv[4]; f1.u[1] = wv[5]; f1.u[2] = wv[6]; f1.u[3] = wv[7];
      pfrag[ntj * 2] = f0.v; pfrag[ntj * 2 + 1] = f1.v;
    }
    // ---- O^T += V^T . P^T  (4 independent chains, depth 4) ----
    #pragma unroll
    for (int ntc = 0; ntc < 4; ++ntc) {
      int r = ntc * 16 + (l31 >> 1);
      int rb = r * 16, r15 = r & 15, c8 = (l31 & 1) * 8;
      #pragma unroll
      for (int kw = 0; kw < 4; ++kw) {
        bf16x8 vf = *(const bf16x8*)&Vbuf[cur][rb + ((c8 + kw * 2 + h5) ^ r15)];
        oacc[ntc] = __builtin_amdgcn_mfma_f32_32x32x16_bf16(vf, pfrag[kw], oacc[ntc], 0, 0, 0);
      }
    }
    __syncthreads();               // next buffer ready, prev reads done
  }

  // ---- close l (own 16 j-rows + partner's), store O/l to [b][o][p] ----
  float linv = 1.0f / (lsum + __shfl_xor(lsum, 32, 64));
  int i = i0 + wl * 32 + l31;
  #pragma unroll
  for (int ntc = 0; ntc < 4; ++ntc)
    #pragma unroll
    for (int r = 0; r < 16; ++r) {
      int c = ntc * 32 + (r & 3) + 8 * (r >> 2) + 4 * h5;
      attws[((size_t)(b * NCH + c * 4 + hh)) * NP + i] = f2bf(oacc[ntc][r] * linv);
    }
}

// ---------------------------------------------------------------- out proj --
__global__ __launch_bounds__(256) void out_proj(
    const unsigned short* __restrict__ attws, const float* __restrict__ Wo,
    const float* __restrict__ bo, const float* __restrict__ in,
    float* __restrict__ out) {
  __shared__ __align__(16) unsigned short Xt[64][136];  // [p][k-chunk]
  int t = threadIdx.x;
  int pt = blockIdx.x & 31, b = blockIdx.x >> 5;
  int p0 = pt * 64;
  int w = t >> 6, lane = t & 63, l31 = lane & 31, h5 = lane >> 5;
  f32x16 acc[2] = {};
  #pragma unroll 1
  for (int k0 = 0; k0 < 4; ++k0) {
    __syncthreads();
    {  // stage att chunk [128 k][64 p] -> Xt[p][k]
      int k = t >> 1, ph = t & 1;
      const unsigned short* src = attws + ((size_t)(b * NCH + k0 * 128 + k)) * NP + p0 + ph * 32;
      union { int4 v[4]; unsigned short u[32]; } uu;
      uu.v[0] = *(const int4*)src;        uu.v[1] = *(const int4*)(src + 8);
      uu.v[2] = *(const int4*)(src + 16); uu.v[3] = *(const int4*)(src + 24);
      #pragma unroll
      for (int e = 0; e < 32; ++e) Xt[ph * 32 + e][k] = uu.u[e];
    }
    __syncthreads();
    #pragma unroll
    for (int ks = 0; ks < 8; ++ks) {
      const float* wr = Wo + (size_t)(w * 32 + l31) * NCH + k0 * 128 + ks * 16 + h5 * 8;
      float4 a = *(const float4*)wr, b4 = *(const float4*)(wr + 4);
      union { bf16x8 v; unsigned u[4]; } uu;
      uu.u[0] = pk2(a.x, a.y); uu.u[1] = pk2(a.z, a.w);
      uu.u[2] = pk2(b4.x, b4.y); uu.u[3] = pk2(b4.z, b4.w);
      #pragma unroll
      for (int nt = 0; nt < 2; ++nt) {
        bf16x8 bf = *(const bf16x8*)&Xt[nt * 32 + l31][ks * 16 + h5 * 8];
        acc[nt] = __builtin_amdgcn_mfma_f32_32x32x16_bf16(uu.v, bf, acc[nt], 0, 0, 0);
      }
    }
  }
  #pragma unroll
  for (int nt = 0; nt < 2; ++nt)
    #pragma unroll
    for (int r = 0; r < 16; ++r) {
      int o = w * 32 + (r & 3) + 8 * (r >> 2) + 4 * h5;
      int p = p0 + nt * 32 + l31;
      size_t idx = ((size_t)(b * NC + o)) * NP + p;
      out[idx] = acc[nt][r] + bo[o] + in[idx];
    }
}

// ------------------------------------------------------------------ launch --
extern "C" void kernel_launch(void* const* d_in, const int* in_sizes, int n_in,
                              void* d_out, int out_size, void* d_ws, size_t ws_size,
                              hipStream_t stream) {
  const float* in    = (const float*)d_in[0];
  const float* gamma = (const float*)d_in[1];
  const float* beta  = (const float*)d_in[2];
  const float* Wq = (const float*)d_in[3];
  const float* bq = (const float*)d_in[4];
  const float* Wk = (const float*)d_in[5];
  const float* bk = (const float*)d_in[6];
  const float* Wv = (const float*)d_in[7];
  const float* bv = (const float*)d_in[8];
  const float* Wo = (const float*)d_in[9];
  const float* bo = (const float*)d_in[10];
  float* out = (float*)d_out;

  // ws: 8KB stats + qT/kT [b][h][p][c] bf16, v/att [b][o][p] bf16, 16MB each
  char* ws = (char*)d_ws;
  float* psum  = (float*)ws;           // 512
  float* psum2 = psum + 512;           // 512
  const size_t QKV_ELEMS = (size_t)NB * NCH * NP;  // 8,388,608
  unsigned short* qws   = (unsigned short*)(ws + 8192);
  unsigned short* kws   = qws + QKV_ELEMS;
  unsigned short* vws   = kws + QKV_ELEMS;
  unsigned short* attws = vws + QKV_ELEMS;

  bn_partial<<<dim3(512), dim3(256), 0, stream>>>(in, psum, psum2);
  qkv_proj<<<dim3(256), dim3(512), 0, stream>>>(
      in, gamma, beta, psum, psum2, Wq, bq, Wk, bk, Wv, bv, qws, kws, vws);
  attn<<<dim3(512), dim3(256), 0, stream>>>(qws, kws, vws, attws);
  out_proj<<<dim3(256), dim3(256), 0, stream>>>(attws, Wo, bo, in, out);
}